// Round 1
// baseline (720.013 us; speedup 1.0000x reference)
//
#include <hip/hip_runtime.h>
#include <hip/hip_bf16.h>
#include <math.h>

#define N_NODES 100000
#define N_EDGES 1600000
#define N_IN 256
#define N_OUT 64

// ---------------------------------------------------------------------------
// GEMM: h = x @ W + b   [N_NODES, N_OUT]
// block = 256 threads (4 waves); each wave computes 8 rows x 64 cols.
// lane j = output column j. W staged in LDS (64KB), read Wlds[k*64+j]
// (consecutive lanes -> consecutive addresses -> conflict-free 2-way).
// x rows read as float4 (wave-uniform address, L1-broadcast).
// 100000 % 32 == 0 so no row guard needed.
// ---------------------------------------------------------------------------
constexpr int ROWS_PER_WAVE = 8;
constexpr int ROWS_PER_BLOCK = 4 * ROWS_PER_WAVE; // 32

__global__ __launch_bounds__(256) void gemm_kernel(const float* __restrict__ x,
                                                   const float* __restrict__ W,
                                                   const float* __restrict__ bias,
                                                   float* __restrict__ h) {
    __shared__ float Wlds[N_IN * N_OUT]; // 64 KB
    const int t = threadIdx.x;
    // cooperative W load: 16384 floats = 4096 float4 over 256 threads
#pragma unroll
    for (int i = 0; i < (N_IN * N_OUT) / (256 * 4); ++i) {
        reinterpret_cast<float4*>(Wlds)[t + i * 256] =
            reinterpret_cast<const float4*>(W)[t + i * 256];
    }
    __syncthreads();

    const int wave = t >> 6;
    const int lane = t & 63;
    const int row0 = blockIdx.x * ROWS_PER_BLOCK + wave * ROWS_PER_WAVE;

    float acc[ROWS_PER_WAVE];
#pragma unroll
    for (int r = 0; r < ROWS_PER_WAVE; ++r) acc[r] = 0.f;

    for (int k = 0; k < N_IN; k += 4) {
        const float w0 = Wlds[(k + 0) * N_OUT + lane];
        const float w1 = Wlds[(k + 1) * N_OUT + lane];
        const float w2 = Wlds[(k + 2) * N_OUT + lane];
        const float w3 = Wlds[(k + 3) * N_OUT + lane];
#pragma unroll
        for (int r = 0; r < ROWS_PER_WAVE; ++r) {
            const float4 xv =
                *reinterpret_cast<const float4*>(&x[(size_t)(row0 + r) * N_IN + k]);
            acc[r] = fmaf(xv.x, w0, acc[r]);
            acc[r] = fmaf(xv.y, w1, acc[r]);
            acc[r] = fmaf(xv.z, w2, acc[r]);
            acc[r] = fmaf(xv.w, w3, acc[r]);
        }
    }
    const float bv = bias[lane];
#pragma unroll
    for (int r = 0; r < ROWS_PER_WAVE; ++r) {
        h[(size_t)(row0 + r) * N_OUT + lane] = acc[r] + bv;
    }
}

// ---------------------------------------------------------------------------
// Edge scatter: one wave per edge. lane j handles output column j.
//   agg[row*64+j] += val * h[col*64+j]   (fp32 global atomics)
// ---------------------------------------------------------------------------
__global__ __launch_bounds__(256) void scatter_kernel(const int* __restrict__ erow,
                                                      const int* __restrict__ ecol,
                                                      const float* __restrict__ eval_,
                                                      const float* __restrict__ h,
                                                      float* __restrict__ agg) {
    const int wid = (int)((blockIdx.x * (size_t)blockDim.x + threadIdx.x) >> 6);
    const int lane = threadIdx.x & 63;
    if (wid >= N_EDGES) return;
    const int r = erow[wid];
    const int c = ecol[wid];
    const float v = eval_[wid];
    const float hv = h[(size_t)c * N_OUT + lane];
    atomicAdd(&agg[(size_t)r * N_OUT + lane], v * hv);
}

// ---------------------------------------------------------------------------
// ELU in-place: x > 0 ? x : exp(x) - 1
// ---------------------------------------------------------------------------
__global__ __launch_bounds__(256) void elu_kernel(float* __restrict__ out) {
    const size_t i = (blockIdx.x * (size_t)blockDim.x + threadIdx.x) * 4;
    if (i >= (size_t)N_NODES * N_OUT) return;
    float4 v = *reinterpret_cast<float4*>(&out[i]);
    v.x = v.x > 0.f ? v.x : expf(v.x) - 1.f;
    v.y = v.y > 0.f ? v.y : expf(v.y) - 1.f;
    v.z = v.z > 0.f ? v.z : expf(v.z) - 1.f;
    v.w = v.w > 0.f ? v.w : expf(v.w) - 1.f;
    *reinterpret_cast<float4*>(&out[i]) = v;
}

extern "C" void kernel_launch(void* const* d_in, const int* in_sizes, int n_in,
                              void* d_out, int out_size, void* d_ws, size_t ws_size,
                              hipStream_t stream) {
    const float* x  = (const float*)d_in[0];
    const int*   er = (const int*)d_in[1];
    const int*   ec = (const int*)d_in[2];
    const float* ev = (const float*)d_in[3];
    const float* W  = (const float*)d_in[4];
    const float* b  = (const float*)d_in[5];
    float* out = (float*)d_out;
    float* h   = (float*)d_ws;   // 100000*64*4 = 25.6 MB scratch

    // agg accumulator = d_out; must zero it (harness poisons with 0xAA)
    hipMemsetAsync(d_out, 0, (size_t)out_size * sizeof(float), stream);

    gemm_kernel<<<N_NODES / ROWS_PER_BLOCK, 256, 0, stream>>>(x, W, b, h);

    // one wave per edge -> 4 edges per 256-thread block
    scatter_kernel<<<(N_EDGES + 3) / 4, 256, 0, stream>>>(er, ec, ev, h, out);

    const size_t nquads = (size_t)N_NODES * N_OUT / 4; // 1.6M
    elu_kernel<<<(nquads + 255) / 256, 256, 0, stream>>>(out);
}

// Round 2
// 545.852 us; speedup vs baseline: 1.3191x; 1.3191x over previous
//
#include <hip/hip_runtime.h>
#include <math.h>

#define N_NODES 100000
#define N_EDGES 1600000
#define N_IN 256
#define N_OUT 64

// ws layout (bytes). Total ~26.9 MB — assumes ws_size >= 27 MB.
#define WS_HBF    0           // bf16 h [100000][64]            12,800,000 B
#define WS_WT     12800000    // bf16 W^T swizzled image         32,768 B
#define WS_CNT    12832768    // int counts[100000]              400,000 B
#define WS_OFFS   13232768    // int offs[100001] (+pad)         400,128 B
#define WS_CUR    13632896    // int cursor[100000]              400,000 B
#define WS_BSUM   14032896    // int blocksums[512]              2,048 B
#define WS_BOFF   14034944    // int blockoffs[512]              2,048 B
#define WS_EDGES  14036992    // int2 sorted edges[1600000]      12,800,000 B

typedef __attribute__((ext_vector_type(8))) __bf16 bf16x8;
typedef __attribute__((ext_vector_type(4))) float f32x4;

static __device__ __forceinline__ unsigned short f2bf(float f) {
    union { float f; unsigned int u; } a; a.f = f;
    unsigned int u = a.u;
    return (unsigned short)((u + 0x7FFFu + ((u >> 16) & 1u)) >> 16); // RNE
}
static __device__ __forceinline__ float bf2f(unsigned short h) {
    union { unsigned int u; float f; } a; a.u = ((unsigned int)h) << 16;
    return a.f;
}

// ---------------------------------------------------------------------------
// W [256][64] fp32 -> W^T bf16, stored as the exact byte image of the LDS
// tile the GEMM wants: row-major Wt[col][k] (64 x 256 bf16, 512 B per col),
// with 16B-chunk XOR swizzle  m' = m ^ (col&7)  (m = k/8) so that the
// B-fragment ds_read_b128 (16 lanes -> 16 cols, 512 B stride) is 2-way max.
// ---------------------------------------------------------------------------
__global__ __launch_bounds__(256) void wconv_kernel(const float* __restrict__ W,
                                                    unsigned short* __restrict__ wt) {
    const int t = threadIdx.x;
    const int n = t >> 2;            // col 0..63
    const int k0 = (t & 3) * 64;
    for (int k = k0; k < k0 + 64; ++k) {
        const unsigned short v = f2bf(W[k * N_OUT + n]);
        const unsigned m = (unsigned)k >> 3;
        const unsigned byte = (unsigned)n * 512u + ((m ^ ((unsigned)n & 7u)) << 4);
        wt[byte / 2 + (k & 7)] = v;
    }
}

// ---------------------------------------------------------------------------
// GEMM h = x @ W + b via v_mfma_f32_16x16x32_bf16, h stored bf16.
// block = 256 (4 waves), each wave owns 16 rows x 64 cols (4 col-tiles).
// A-frag: lane holds x[row0+(lane&15)][ks*32+(lane>>4)*8 + 0..7] (fp32->bf16).
// B-frag: ds_read_b128 from swizzled Wt LDS image.
// C/D: col = lane&15, row = (lane>>4)*4 + reg  [m89-verified].
// ---------------------------------------------------------------------------
__global__ __launch_bounds__(256) void gemm_kernel(const float* __restrict__ x,
                                                   const float4* __restrict__ wt,
                                                   const float* __restrict__ bias,
                                                   unsigned short* __restrict__ hbf) {
    __shared__ unsigned short Wlds[N_IN * N_OUT]; // 32 KB, swizzled image
    const int t = threadIdx.x;
#pragma unroll
    for (int i = 0; i < 8; ++i)
        reinterpret_cast<float4*>(Wlds)[t + i * 256] = wt[t + i * 256];
    __syncthreads();

    const int wave = t >> 6, lane = t & 63;
    const int lrow = lane & 15, q = lane >> 4;
    const int r0 = blockIdx.x * 64 + wave * 16;
    int row = r0 + lrow;
    if (row >= N_NODES) row = N_NODES - 1;       // clamp loads; stores guarded
    const float* xp = x + (size_t)row * N_IN + q * 8;

    const char* ldsb = reinterpret_cast<const char*>(Wlds);
    unsigned colbase[4], colx[4];
#pragma unroll
    for (int c = 0; c < 4; ++c) {
        const unsigned col = c * 16 + lrow;
        colbase[c] = col * 512u;
        colx[c] = col & 7u;
    }

    f32x4 acc[4];
#pragma unroll
    for (int c = 0; c < 4; ++c) acc[c] = (f32x4){0.f, 0.f, 0.f, 0.f};

#pragma unroll
    for (int ks = 0; ks < 8; ++ks) {
        const float4 a0 = *reinterpret_cast<const float4*>(xp + ks * 32);
        const float4 a1 = *reinterpret_cast<const float4*>(xp + ks * 32 + 4);
        union { bf16x8 v; unsigned short u[8]; } af;
        af.u[0] = f2bf(a0.x); af.u[1] = f2bf(a0.y);
        af.u[2] = f2bf(a0.z); af.u[3] = f2bf(a0.w);
        af.u[4] = f2bf(a1.x); af.u[5] = f2bf(a1.y);
        af.u[6] = f2bf(a1.z); af.u[7] = f2bf(a1.w);
        const unsigned m = ks * 4 + q;
#pragma unroll
        for (int c = 0; c < 4; ++c) {
            const unsigned byte = colbase[c] + ((m ^ colx[c]) << 4);
            const bf16x8 bv = *reinterpret_cast<const bf16x8*>(ldsb + byte);
            acc[c] = __builtin_amdgcn_mfma_f32_16x16x32_bf16(af.v, bv, acc[c], 0, 0, 0);
        }
    }

#pragma unroll
    for (int c = 0; c < 4; ++c) {
        const int col = c * 16 + lrow;
        const float bv = bias[col];
#pragma unroll
        for (int mm = 0; mm < 4; ++mm) {
            const int rr = r0 + q * 4 + mm;
            if (rr < N_NODES)
                hbf[(size_t)rr * N_OUT + col] = f2bf(acc[c][mm] + bv);
        }
    }
}

// --------------------------- CSR build ------------------------------------
__global__ __launch_bounds__(256) void hist_kernel(const int* __restrict__ er,
                                                   int* __restrict__ cnt) {
    const int e = blockIdx.x * 256 + threadIdx.x;  // grid exact: 6250*256
    atomicAdd(&cnt[er[e]], 1);
}

__global__ __launch_bounds__(256) void scanb_kernel(const int* __restrict__ cnt,
                                                    int* __restrict__ offs,
                                                    int* __restrict__ bsum) {
    __shared__ int s[256];
    const int t = threadIdx.x;
    const int i = blockIdx.x * 256 + t;
    const int v = (i < N_NODES) ? cnt[i] : 0;
    s[t] = v; __syncthreads();
#pragma unroll
    for (int d = 1; d < 256; d <<= 1) {
        const int u = (t >= d) ? s[t - d] : 0;
        __syncthreads();
        s[t] += u;
        __syncthreads();
    }
    if (i < N_NODES) offs[i] = s[t] - v;   // exclusive
    if (t == 255) bsum[blockIdx.x] = s[255];
}

__global__ __launch_bounds__(512) void scans_kernel(const int* __restrict__ bsum,
                                                    int* __restrict__ boffs) {
    __shared__ int s[512];
    const int t = threadIdx.x;
    const int v = (t < 391) ? bsum[t] : 0;
    s[t] = v; __syncthreads();
#pragma unroll
    for (int d = 1; d < 512; d <<= 1) {
        const int u = (t >= d) ? s[t - d] : 0;
        __syncthreads();
        s[t] += u;
        __syncthreads();
    }
    boffs[t] = s[t] - v;
}

__global__ __launch_bounds__(256) void addoff_kernel(int* __restrict__ offs,
                                                     const int* __restrict__ boffs,
                                                     int* __restrict__ cursor) {
    const int i = blockIdx.x * 256 + threadIdx.x;
    if (i < N_NODES) {
        const int o = offs[i] + boffs[blockIdx.x];
        offs[i] = o;
        cursor[i] = o;
    }
    if (i == 0) offs[N_NODES] = N_EDGES;
}

__global__ __launch_bounds__(256) void esort_kernel(const int* __restrict__ er,
                                                    const int* __restrict__ ec,
                                                    const float* __restrict__ ev,
                                                    int* __restrict__ cursor,
                                                    int2* __restrict__ edges) {
    const int e = blockIdx.x * 256 + threadIdx.x;  // grid exact
    const int r = er[e];
    const int pos = atomicAdd(&cursor[r], 1);
    edges[pos] = make_int2(ec[e], __float_as_int(ev[e]));
}

// ------------------- pull aggregation + fused ELU --------------------------
// one wave per node; lane j = output column j. Per edge: broadcast int2 read
// (col,valbits) + coalesced 128 B bf16 gather of h row. fp32 accumulate.
__global__ __launch_bounds__(256) void agg_kernel(const int* __restrict__ offs,
                                                  const int2* __restrict__ edges,
                                                  const unsigned short* __restrict__ hbf,
                                                  float* __restrict__ out) {
    const int wave = threadIdx.x >> 6, lane = threadIdx.x & 63;
    const int n = blockIdx.x * 4 + wave;           // grid exact: 25000*4
    const int s = offs[n], e = offs[n + 1];
    float acc = 0.f;
    if (s < e) {
        int2 cv = edges[s];
        for (int i = s; i < e; ++i) {
            const int2 nx = (i + 1 < e) ? edges[i + 1] : cv;   // prefetch
            const float hv = bf2f(hbf[(size_t)cv.x * N_OUT + lane]);
            acc = fmaf(__int_as_float(cv.y), hv, acc);
            cv = nx;
        }
    }
    out[(size_t)n * N_OUT + lane] = acc > 0.f ? acc : expf(acc) - 1.f;
}

extern "C" void kernel_launch(void* const* d_in, const int* in_sizes, int n_in,
                              void* d_out, int out_size, void* d_ws, size_t ws_size,
                              hipStream_t stream) {
    const float* x  = (const float*)d_in[0];
    const int*   er = (const int*)d_in[1];
    const int*   ec = (const int*)d_in[2];
    const float* ev = (const float*)d_in[3];
    const float* W  = (const float*)d_in[4];
    const float* b  = (const float*)d_in[5];
    float* out = (float*)d_out;
    char* ws = (char*)d_ws;

    unsigned short* hbf = (unsigned short*)(ws + WS_HBF);
    unsigned short* wt  = (unsigned short*)(ws + WS_WT);
    int*  cnt    = (int*)(ws + WS_CNT);
    int*  offs   = (int*)(ws + WS_OFFS);
    int*  cursor = (int*)(ws + WS_CUR);
    int*  bsum   = (int*)(ws + WS_BSUM);
    int*  boffs  = (int*)(ws + WS_BOFF);
    int2* edges  = (int2*)(ws + WS_EDGES);

    hipMemsetAsync(cnt, 0, N_NODES * sizeof(int), stream);

    hist_kernel<<<N_EDGES / 256, 256, 0, stream>>>(er, cnt);
    wconv_kernel<<<1, 256, 0, stream>>>(W, wt);
    scanb_kernel<<<391, 256, 0, stream>>>(cnt, offs, bsum);
    scans_kernel<<<1, 512, 0, stream>>>(bsum, boffs);
    addoff_kernel<<<391, 256, 0, stream>>>(offs, boffs, cursor);
    esort_kernel<<<N_EDGES / 256, 256, 0, stream>>>(er, ec, ev, cursor, edges);
    gemm_kernel<<<(N_NODES + 63) / 64, 256, 0, stream>>>(x, (const float4*)wt, b, hbf);
    agg_kernel<<<N_NODES / 4, 256, 0, stream>>>(offs, edges, hbf, out);
}

// Round 3
// 427.472 us; speedup vs baseline: 1.6843x; 1.2769x over previous
//
#include <hip/hip_runtime.h>
#include <math.h>

#define N_NODES 100000
#define N_EDGES 1600000
#define N_IN 256
#define N_OUT 64

// ws layout (bytes). Total ~26.9 MB — assumes ws_size >= 27 MB.
#define WS_HBF    0           // bf16 h [100000][64]            12,800,000 B
#define WS_WT     12800000    // bf16 W^T swizzled image         32,768 B
#define WS_CNT    12832768    // int counts[100000]              400,000 B
#define WS_OFFS   13232768    // int offs[100001] (+pad)         400,128 B
#define WS_CUR    13632896    // int cursor[100000]              400,000 B
#define WS_BSUM   14032896    // int blocksums[512]              2,048 B
#define WS_BOFF   14034944    // int blockoffs[512]              2,048 B
#define WS_EDGES  14036992    // int2 sorted edges[1600000]      12,800,000 B

typedef __attribute__((ext_vector_type(8))) __bf16 bf16x8;
typedef __attribute__((ext_vector_type(4))) float f32x4;

static __device__ __forceinline__ unsigned short f2bf(float f) {
    union { float f; unsigned int u; } a; a.f = f;
    unsigned int u = a.u;
    return (unsigned short)((u + 0x7FFFu + ((u >> 16) & 1u)) >> 16); // RNE
}
static __device__ __forceinline__ float bf2f(unsigned short h) {
    union { unsigned int u; float f; } a; a.u = ((unsigned int)h) << 16;
    return a.f;
}

// ---------------------------------------------------------------------------
// W [256][64] fp32 -> W^T bf16 swizzled LDS image (see gemm_kernel).
// One thread per element; 64 blocks x 256 threads.
// ---------------------------------------------------------------------------
__global__ __launch_bounds__(256) void wconv_kernel(const float* __restrict__ W,
                                                    unsigned short* __restrict__ wt) {
    const int g = blockIdx.x * 256 + threadIdx.x;   // 0..16383
    const int k = g >> 6, n = g & 63;
    const unsigned short v = f2bf(W[k * N_OUT + n]);
    const unsigned m = (unsigned)k >> 3;
    const unsigned byte = (unsigned)n * 512u + ((m ^ ((unsigned)n & 7u)) << 4);
    wt[byte / 2 + (k & 7)] = v;
}

// ---------------------------------------------------------------------------
// GEMM h = x @ W + b via v_mfma_f32_16x16x32_bf16, h stored bf16.
// block = 256 (4 waves), each wave owns 16 rows x 64 cols (4 col-tiles).
// A-frag: lane holds x[row0+(lane&15)][ks*32+(lane>>4)*8 + 0..7] (fp32->bf16).
// B-frag: ds_read_b128 from swizzled Wt LDS image.
// C/D: col = lane&15, row = (lane>>4)*4 + reg  [m89-verified].
// ---------------------------------------------------------------------------
__global__ __launch_bounds__(256) void gemm_kernel(const float* __restrict__ x,
                                                   const float4* __restrict__ wt,
                                                   const float* __restrict__ bias,
                                                   unsigned short* __restrict__ hbf) {
    __shared__ unsigned short Wlds[N_IN * N_OUT]; // 32 KB, swizzled image
    const int t = threadIdx.x;
#pragma unroll
    for (int i = 0; i < 8; ++i)
        reinterpret_cast<float4*>(Wlds)[t + i * 256] = wt[t + i * 256];
    __syncthreads();

    const int wave = t >> 6, lane = t & 63;
    const int lrow = lane & 15, q = lane >> 4;
    const int r0 = blockIdx.x * 64 + wave * 16;
    int row = r0 + lrow;
    if (row >= N_NODES) row = N_NODES - 1;       // clamp loads; stores guarded
    const float* xp = x + (size_t)row * N_IN + q * 8;

    const char* ldsb = reinterpret_cast<const char*>(Wlds);
    unsigned colbase[4], colx[4];
#pragma unroll
    for (int c = 0; c < 4; ++c) {
        const unsigned col = c * 16 + lrow;
        colbase[c] = col * 512u;
        colx[c] = col & 7u;
    }

    f32x4 acc[4];
#pragma unroll
    for (int c = 0; c < 4; ++c) acc[c] = (f32x4){0.f, 0.f, 0.f, 0.f};

#pragma unroll
    for (int ks = 0; ks < 8; ++ks) {
        const float4 a0 = *reinterpret_cast<const float4*>(xp + ks * 32);
        const float4 a1 = *reinterpret_cast<const float4*>(xp + ks * 32 + 4);
        union { bf16x8 v; unsigned short u[8]; } af;
        af.u[0] = f2bf(a0.x); af.u[1] = f2bf(a0.y);
        af.u[2] = f2bf(a0.z); af.u[3] = f2bf(a0.w);
        af.u[4] = f2bf(a1.x); af.u[5] = f2bf(a1.y);
        af.u[6] = f2bf(a1.z); af.u[7] = f2bf(a1.w);
        const unsigned m = ks * 4 + q;
#pragma unroll
        for (int c = 0; c < 4; ++c) {
            const unsigned byte = colbase[c] + ((m ^ colx[c]) << 4);
            const bf16x8 bv = *reinterpret_cast<const bf16x8*>(ldsb + byte);
            acc[c] = __builtin_amdgcn_mfma_f32_16x16x32_bf16(af.v, bv, acc[c], 0, 0, 0);
        }
    }

#pragma unroll
    for (int c = 0; c < 4; ++c) {
        const int col = c * 16 + lrow;
        const float bv = bias[col];
#pragma unroll
        for (int mm = 0; mm < 4; ++mm) {
            const int rr = r0 + q * 4 + mm;
            if (rr < N_NODES)
                hbf[(size_t)rr * N_OUT + col] = f2bf(acc[c][mm] + bv);
        }
    }
}

// --------------------------- CSR build ------------------------------------
__global__ __launch_bounds__(256) void hist_kernel(const int* __restrict__ er,
                                                   int* __restrict__ cnt) {
    const int e = blockIdx.x * 256 + threadIdx.x;  // grid exact: 6250*256
    atomicAdd(&cnt[er[e]], 1);
}

__global__ __launch_bounds__(256) void scanb_kernel(const int* __restrict__ cnt,
                                                    int* __restrict__ offs,
                                                    int* __restrict__ bsum) {
    __shared__ int s[256];
    const int t = threadIdx.x;
    const int i = blockIdx.x * 256 + t;
    const int v = (i < N_NODES) ? cnt[i] : 0;
    s[t] = v; __syncthreads();
#pragma unroll
    for (int d = 1; d < 256; d <<= 1) {
        const int u = (t >= d) ? s[t - d] : 0;
        __syncthreads();
        s[t] += u;
        __syncthreads();
    }
    if (i < N_NODES) offs[i] = s[t] - v;   // exclusive
    if (t == 255) bsum[blockIdx.x] = s[255];
}

__global__ __launch_bounds__(512) void scans_kernel(const int* __restrict__ bsum,
                                                    int* __restrict__ boffs) {
    __shared__ int s[512];
    const int t = threadIdx.x;
    const int v = (t < 391) ? bsum[t] : 0;
    s[t] = v; __syncthreads();
#pragma unroll
    for (int d = 1; d < 512; d <<= 1) {
        const int u = (t >= d) ? s[t - d] : 0;
        __syncthreads();
        s[t] += u;
        __syncthreads();
    }
    boffs[t] = s[t] - v;
}

__global__ __launch_bounds__(256) void addoff_kernel(int* __restrict__ offs,
                                                     const int* __restrict__ boffs,
                                                     int* __restrict__ cursor) {
    const int i = blockIdx.x * 256 + threadIdx.x;
    if (i < N_NODES) {
        const int o = offs[i] + boffs[blockIdx.x];
        offs[i] = o;
        cursor[i] = o;
    }
    if (i == 0) offs[N_NODES] = N_EDGES;
}

__global__ __launch_bounds__(256) void esort_kernel(const int* __restrict__ er,
                                                    const int* __restrict__ ec,
                                                    const float* __restrict__ ev,
                                                    int* __restrict__ cursor,
                                                    int2* __restrict__ edges) {
    const int e = blockIdx.x * 256 + threadIdx.x;  // grid exact
    const int r = er[e];
    const int pos = atomicAdd(&cursor[r], 1);
    edges[pos] = make_int2(ec[e], __float_as_int(ev[e]));
}

// ------------------- pull aggregation + fused ELU --------------------------
// one wave per node; lane j = output column j. 4-way ILP: 4 independent
// edge reads -> 4 independent 128B h-row gathers in flight -> 4 accumulators.
__global__ __launch_bounds__(256) void agg_kernel(const int* __restrict__ offs,
                                                  const int2* __restrict__ edges,
                                                  const unsigned short* __restrict__ hbf,
                                                  float* __restrict__ out) {
    const int wave = threadIdx.x >> 6, lane = threadIdx.x & 63;
    const int n = blockIdx.x * 4 + wave;           // grid exact: 25000*4
    const int s = offs[n], e = offs[n + 1];
    float a0 = 0.f, a1 = 0.f, a2 = 0.f, a3 = 0.f;
    int i = s;
    for (; i + 4 <= e; i += 4) {
        const int2 e0 = edges[i + 0];
        const int2 e1 = edges[i + 1];
        const int2 e2 = edges[i + 2];
        const int2 e3 = edges[i + 3];
        const float h0 = bf2f(hbf[(size_t)e0.x * N_OUT + lane]);
        const float h1 = bf2f(hbf[(size_t)e1.x * N_OUT + lane]);
        const float h2 = bf2f(hbf[(size_t)e2.x * N_OUT + lane]);
        const float h3 = bf2f(hbf[(size_t)e3.x * N_OUT + lane]);
        a0 = fmaf(__int_as_float(e0.y), h0, a0);
        a1 = fmaf(__int_as_float(e1.y), h1, a1);
        a2 = fmaf(__int_as_float(e2.y), h2, a2);
        a3 = fmaf(__int_as_float(e3.y), h3, a3);
    }
    for (; i < e; ++i) {
        const int2 cv = edges[i];
        a0 = fmaf(__int_as_float(cv.y), bf2f(hbf[(size_t)cv.x * N_OUT + lane]), a0);
    }
    const float acc = (a0 + a1) + (a2 + a3);
    out[(size_t)n * N_OUT + lane] = acc > 0.f ? acc : expf(acc) - 1.f;
}

extern "C" void kernel_launch(void* const* d_in, const int* in_sizes, int n_in,
                              void* d_out, int out_size, void* d_ws, size_t ws_size,
                              hipStream_t stream) {
    const float* x  = (const float*)d_in[0];
    const int*   er = (const int*)d_in[1];
    const int*   ec = (const int*)d_in[2];
    const float* ev = (const float*)d_in[3];
    const float* W  = (const float*)d_in[4];
    const float* b  = (const float*)d_in[5];
    float* out = (float*)d_out;
    char* ws = (char*)d_ws;

    unsigned short* hbf = (unsigned short*)(ws + WS_HBF);
    unsigned short* wt  = (unsigned short*)(ws + WS_WT);
    int*  cnt    = (int*)(ws + WS_CNT);
    int*  offs   = (int*)(ws + WS_OFFS);
    int*  cursor = (int*)(ws + WS_CUR);
    int*  bsum   = (int*)(ws + WS_BSUM);
    int*  boffs  = (int*)(ws + WS_BOFF);
    int2* edges  = (int2*)(ws + WS_EDGES);

    hipMemsetAsync(cnt, 0, N_NODES * sizeof(int), stream);

    hist_kernel<<<N_EDGES / 256, 256, 0, stream>>>(er, cnt);
    wconv_kernel<<<64, 256, 0, stream>>>(W, wt);
    scanb_kernel<<<391, 256, 0, stream>>>(cnt, offs, bsum);
    scans_kernel<<<1, 512, 0, stream>>>(bsum, boffs);
    addoff_kernel<<<391, 256, 0, stream>>>(offs, boffs, cursor);
    esort_kernel<<<N_EDGES / 256, 256, 0, stream>>>(er, ec, ev, cursor, edges);
    gemm_kernel<<<(N_NODES + 63) / 64, 256, 0, stream>>>(x, (const float4*)wt, b, hbf);
    agg_kernel<<<N_NODES / 4, 256, 0, stream>>>(offs, edges, hbf, out);
}